// Round 1
// baseline (113.076 us; speedup 1.0000x reference)
//
#include <hip/hip_runtime.h>

#define E_TOTAL 320000
#define NNODES  10000
#define HID     256
#define NCLS    10
#define BM      64

typedef __attribute__((ext_vector_type(4))) float f32x4;
typedef __attribute__((ext_vector_type(8))) __bf16 bf16x8;
typedef __attribute__((ext_vector_type(8))) unsigned short u16x8;

static __device__ __forceinline__ unsigned short f2bf(float f) {
  unsigned u = __builtin_bit_cast(unsigned, f);
  u += 0x7fffu + ((u >> 16) & 1u);
  return (unsigned short)(u >> 16);
}

// ---- prep: x f32 -> bf16 (row-major [NNODES][HID]) ----
__global__ void k_x2bf(const float* __restrict__ x, unsigned short* __restrict__ xbf) {
  int i = blockIdx.x * blockDim.x + threadIdx.x;  // one thread per 8 elems
  const f32x4* s = (const f32x4*)x + (size_t)i * 2;
  f32x4 a = s[0], b = s[1];
  u16x8 o;
  o[0]=f2bf(a[0]); o[1]=f2bf(a[1]); o[2]=f2bf(a[2]); o[3]=f2bf(a[3]);
  o[4]=f2bf(b[0]); o[5]=f2bf(b[1]); o[6]=f2bf(b[2]); o[7]=f2bf(b[3]);
  *((u16x8*)xbf + i) = o;
}

// ---- prep: W1 [512][256] f32 -> MFMA B-fragment layout bf16 ----
// frag id = cb*16 + kk  (cb: 16-col block 0..15, kk: 32-k block 0..15)
// elem ((cb*16+kk)*64 + lane)*8 + j = W1[kk*32 + 8*(lane>>4) + j][cb*16 + (lane&15)]
__global__ void k_w1frag(const float* __restrict__ W1, unsigned short* __restrict__ w1f) {
  int gid = blockIdx.x * blockDim.x + threadIdx.x;  // 16384
  int l = gid & 63, kk = (gid >> 6) & 15, cb = gid >> 10;
  int kbase = kk * 32 + (l >> 4) * 8;
  int col = cb * 16 + (l & 15);
  u16x8 o;
#pragma unroll
  for (int j = 0; j < 8; ++j) o[j] = f2bf(W1[(size_t)(kbase + j) * HID + col]);
  *((u16x8*)w1f + gid) = o;
}

// ---- prep: W2 [256][10] f32 -> padded (16-col) MFMA B-fragment layout bf16 ----
__global__ void k_w2frag(const float* __restrict__ W2, unsigned short* __restrict__ w2f) {
  int gid = blockIdx.x * blockDim.x + threadIdx.x;  // 512
  int l = gid & 63, kk = gid >> 6;                  // kk 0..7
  int kbase = kk * 32 + (l >> 4) * 8;
  int c = l & 15;
  u16x8 o;
#pragma unroll
  for (int j = 0; j < 8; ++j)
    o[j] = (c < NCLS) ? f2bf(W2[(size_t)(kbase + j) * NCLS + c]) : (unsigned short)0;
  *((u16x8*)w2f + gid) = o;
}

// ---- main fused kernel ----
__global__ __launch_bounds__(256, 3) void k_main(
    const int* __restrict__ ei,            // [2][E] int32
    const unsigned short* __restrict__ xbf,
    const unsigned short* __restrict__ w1f,
    const unsigned short* __restrict__ w2f,
    const float* __restrict__ b1,
    const float* __restrict__ b2,
    float* __restrict__ out)               // [E][10] f32
{
  __shared__ __align__(16) unsigned short ldsA[2][BM * 64];   // 2 x 8KB, XOR-swizzled
  __shared__ __align__(16) unsigned short ldsH[BM][HID + 8];  // bf16 h, padded
  __shared__ int ldsIdx[2][BM];

  const int tid  = threadIdx.x;
  const int lane = tid & 63;
  const int wv   = tid >> 6;       // wave 0..3
  const int e0   = blockIdx.x * BM;
  const int l15  = lane & 15;
  const int lhi  = lane >> 4;

  if (tid < 128) {
    int which = tid >> 6;          // 0=src, 1=dst
    int r = tid & 63;
    ldsIdx[which][r] = ei[which * E_TOTAL + e0 + r];
  }
  __syncthreads();

  f32x4 acc[4][4] = {};

  // stage A k-tile kb (64 cols) into ldsA[buf]; linear LDS dest, inverse-swizzled global src
  auto stageA = [&](int kb, int buf) {
    int which = kb >> 2;
    int col0 = (kb & 3) * 64;
#pragma unroll
    for (int i = 0; i < 2; ++i) {
      int r = wv * 16 + i * 8 + (lane >> 3);     // 8 rows per instr, 8 lanes (16B) per row
      int idx = ldsIdx[which][r];
      int usrc = (lane & 7) ^ (r & 7);           // inverse (involution) of read swizzle
      const unsigned short* g = xbf + (size_t)idx * HID + col0 + usrc * 8;
      unsigned short* lp = &ldsA[buf][(wv * 16 + i * 8) * 64];
      __builtin_amdgcn_global_load_lds(
          (const __attribute__((address_space(1))) unsigned int*)g,
          (__attribute__((address_space(3))) unsigned int*)lp,
          16, 0, 0);
    }
  };

  stageA(0, 0);

  for (int kb = 0; kb < 8; ++kb) {
    int buf = kb & 1;
    __syncthreads();                    // tile kb staged (vmcnt drain) + prev reads done
    if (kb < 7) stageA(kb + 1, buf ^ 1);

    // B fragments direct from L2 (w1f is fragment-layout)
    bf16x8 bfr[2][4];
#pragma unroll
    for (int ks = 0; ks < 2; ++ks)
#pragma unroll
      for (int n = 0; n < 4; ++n) {
        int cb = wv * 4 + n;
        int kk = kb * 2 + ks;
        bfr[ks][n] = *(const bf16x8*)(w1f + ((size_t)(cb * 16 + kk) * 64 + lane) * 8);
      }

#pragma unroll
    for (int ks = 0; ks < 2; ++ks) {
      bf16x8 afr[4];
#pragma unroll
      for (int m = 0; m < 4; ++m) {
        int row = m * 16 + l15;
        int boff = row * 128 + ((ks * 64 + lhi * 16) ^ ((row & 7) << 4));
        afr[m] = *(const bf16x8*)((const char*)&ldsA[buf][0] + boff);
      }
#pragma unroll
      for (int m = 0; m < 4; ++m)
#pragma unroll
        for (int n = 0; n < 4; ++n)
          acc[m][n] = __builtin_amdgcn_mfma_f32_16x16x32_bf16(afr[m], bfr[ks][n], acc[m][n], 0, 0, 0);
    }
  }

  // epilogue GEMM1: + b1, ReLU, stash h as bf16 in LDS
  float b1v[4];
#pragma unroll
  for (int n = 0; n < 4; ++n) b1v[n] = b1[wv * 64 + n * 16 + l15];

#pragma unroll
  for (int m = 0; m < 4; ++m)
#pragma unroll
    for (int n = 0; n < 4; ++n)
#pragma unroll
      for (int r = 0; r < 4; ++r) {
        int row = m * 16 + lhi * 4 + r;
        int col = wv * 64 + n * 16 + l15;
        float v = acc[m][n][r] + b1v[n];
        ldsH[row][col] = f2bf(fmaxf(v, 0.f));
      }
  __syncthreads();

  // GEMM2: wave wv computes logits for rows wv*16..wv*16+15 (K=256, N=16 padded)
  f32x4 lg = {0.f, 0.f, 0.f, 0.f};
#pragma unroll
  for (int kk = 0; kk < 8; ++kk) {
    int row = wv * 16 + l15;
    int k = kk * 32 + lhi * 8;
    bf16x8 a = *(const bf16x8*)&ldsH[row][k];
    bf16x8 b = *(const bf16x8*)(w2f + ((size_t)kk * 64 + lane) * 8);
    lg = __builtin_amdgcn_mfma_f32_16x16x32_bf16(a, b, lg, 0, 0, 0);
  }

  // + b2, log_softmax across the 16-lane col group (cols 10..15 are padding)
  bool valid = (l15 < NCLS);
  float bias = valid ? b2[l15] : 0.f;
#pragma unroll
  for (int r = 0; r < 4; ++r) {
    float v = lg[r] + bias;
    float mv = valid ? v : -1e30f;
#pragma unroll
    for (int s = 1; s < 16; s <<= 1) mv = fmaxf(mv, __shfl_xor(mv, s, 64));
    float ev = valid ? __expf(v - mv) : 0.f;
    float sv = ev;
#pragma unroll
    for (int s = 1; s < 16; s <<= 1) sv += __shfl_xor(sv, s, 64);
    float res = v - mv - __logf(sv);
    if (valid) out[(size_t)(e0 + wv * 16 + lhi * 4 + r) * NCLS + l15] = res;
  }
}

extern "C" void kernel_launch(void* const* d_in, const int* in_sizes, int n_in,
                              void* d_out, int out_size, void* d_ws, size_t ws_size,
                              hipStream_t stream) {
  const float* x  = (const float*)d_in[0];
  const int*   ei = (const int*)d_in[1];
  const float* W1 = (const float*)d_in[2];
  const float* b1 = (const float*)d_in[3];
  const float* W2 = (const float*)d_in[4];
  const float* b2 = (const float*)d_in[5];
  float* out = (float*)d_out;

  unsigned short* xbf = (unsigned short*)d_ws;               // 2,560,000 elems (5,120,000 B)
  unsigned short* w1f = xbf + (size_t)NNODES * HID;          // 131,072 elems (262,144 B)
  unsigned short* w2f = w1f + (size_t)512 * HID;             // 4,096 elems (8,192 B)

  k_x2bf<<<NNODES * HID / 8 / 256, 256, 0, stream>>>(x, xbf);
  k_w1frag<<<64, 256, 0, stream>>>(W1, w1f);
  k_w2frag<<<2, 256, 0, stream>>>(W2, w2f);
  k_main<<<E_TOTAL / BM, 256, 0, stream>>>(ei, xbf, w1f, w2f, b1, b2, out);
}

// Round 2
// 78.718 us; speedup vs baseline: 1.4365x; 1.4365x over previous
//
#include <hip/hip_runtime.h>

#define E_TOTAL 320000
#define NNODES  10000
#define HID     256
#define NCLS    10

typedef __attribute__((ext_vector_type(4))) float f32x4;
typedef __attribute__((ext_vector_type(8))) __bf16 bf16x8;
typedef __attribute__((ext_vector_type(8))) unsigned short u16x8;

static __device__ __forceinline__ unsigned short f2bf(float f) {
  unsigned u = __builtin_bit_cast(unsigned, f);
  u += 0x7fffu + ((u >> 16) & 1u);
  return (unsigned short)(u >> 16);
}
static __device__ __forceinline__ float bf2f(unsigned short h) {
  return __builtin_bit_cast(float, (unsigned)h << 16);
}

// ---- prep: x f32 -> bf16 (row-major [NNODES][HID]) ----
__global__ void k_x2bf(const float* __restrict__ x, unsigned short* __restrict__ xbf) {
  int i = blockIdx.x * blockDim.x + threadIdx.x;  // one thread per 8 elems
  const f32x4* s = (const f32x4*)x + (size_t)i * 2;
  f32x4 a = s[0], b = s[1];
  u16x8 o;
  o[0]=f2bf(a[0]); o[1]=f2bf(a[1]); o[2]=f2bf(a[2]); o[3]=f2bf(a[3]);
  o[4]=f2bf(b[0]); o[5]=f2bf(b[1]); o[6]=f2bf(b[2]); o[7]=f2bf(b[3]);
  *((u16x8*)xbf + i) = o;
}

// ---- prep: W1 [512][256] -> B-fragment layout for the node-GEMM ----
// frag f = (half*16 + cb)*8 + kk ; elem (f*64+l)*8+j =
//   W1[half*256 + kk*32 + 8*(l>>4) + j][cb*16 + (l&15)]
__global__ void k_w1frag(const float* __restrict__ W1, unsigned short* __restrict__ w1f) {
  int gid = blockIdx.x * blockDim.x + threadIdx.x;  // 16384
  int l = gid & 63, kk = (gid >> 6) & 7, cb = (gid >> 9) & 15, half = gid >> 13;
  int kbase = half * 256 + kk * 32 + (l >> 4) * 8;
  int col = cb * 16 + (l & 15);
  u16x8 o;
#pragma unroll
  for (int j = 0; j < 8; ++j) o[j] = f2bf(W1[(size_t)(kbase + j) * HID + col]);
  *((u16x8*)w1f + gid) = o;
}

// ---- prep: W2 [256][10] -> padded (16-col) B-fragment layout bf16 ----
__global__ void k_w2frag(const float* __restrict__ W2, unsigned short* __restrict__ w2f) {
  int gid = blockIdx.x * blockDim.x + threadIdx.x;  // 512
  int l = gid & 63, kk = gid >> 6;                  // kk 0..7
  int kbase = kk * 32 + (l >> 4) * 8;
  int c = l & 15;
  u16x8 o;
#pragma unroll
  for (int j = 0; j < 8; ++j)
    o[j] = (c < NCLS) ? f2bf(W2[(size_t)(kbase + j) * NCLS + c]) : (unsigned short)0;
  *((u16x8*)w2f + gid) = o;
}

// ---- node GEMM: Y[n][half*256+col] = sum_k x[n][k]*W1[half*256+k][col] (+b1 if half==0)
// grid (157, 2), 256 threads. Tile 64 rows x 256 cols, K=256 (4 steps of 64).
__global__ __launch_bounds__(256, 3) void k_prep(
    const unsigned short* __restrict__ xbf,
    const unsigned short* __restrict__ w1f,
    const float* __restrict__ b1,
    unsigned short* __restrict__ Y)           // [NNODES][512] bf16
{
  __shared__ __align__(16) unsigned short ldsA[2][64 * 64];  // XOR-swizzled tiles

  const int tid  = threadIdx.x;
  const int lane = tid & 63;
  const int wv   = tid >> 6;
  const int n0   = blockIdx.x * 64;
  const int half = blockIdx.y;
  const int l15  = lane & 15;
  const int lhi  = lane >> 4;

  f32x4 acc[4][4] = {};

  auto stageA = [&](int kb, int buf) {
    int col0 = kb * 64;
#pragma unroll
    for (int i = 0; i < 2; ++i) {
      int r = wv * 16 + i * 8 + (lane >> 3);
      int gr = n0 + r; if (gr > NNODES - 1) gr = NNODES - 1;
      int usrc = (lane & 7) ^ (r & 7);
      const unsigned short* g = xbf + (size_t)gr * HID + col0 + usrc * 8;
      unsigned short* lp = &ldsA[buf][(wv * 16 + i * 8) * 64];
      __builtin_amdgcn_global_load_lds(
          (const __attribute__((address_space(1))) unsigned int*)g,
          (__attribute__((address_space(3))) unsigned int*)lp,
          16, 0, 0);
    }
  };

  stageA(0, 0);

  for (int kb = 0; kb < 4; ++kb) {
    int buf = kb & 1;
    __syncthreads();
    if (kb < 3) stageA(kb + 1, buf ^ 1);

    bf16x8 bfr[2][4];
#pragma unroll
    for (int ks = 0; ks < 2; ++ks)
#pragma unroll
      for (int n = 0; n < 4; ++n) {
        int cb = wv * 4 + n;
        int kk = kb * 2 + ks;
        int f = (half * 16 + cb) * 8 + kk;
        bfr[ks][n] = *(const bf16x8*)(w1f + ((size_t)f * 64 + lane) * 8);
      }

#pragma unroll
    for (int ks = 0; ks < 2; ++ks) {
      bf16x8 afr[4];
#pragma unroll
      for (int m = 0; m < 4; ++m) {
        int row = m * 16 + l15;
        int boff = row * 128 + ((ks * 64 + lhi * 16) ^ ((row & 7) << 4));
        afr[m] = *(const bf16x8*)((const char*)&ldsA[buf][0] + boff);
      }
#pragma unroll
      for (int m = 0; m < 4; ++m)
#pragma unroll
        for (int n = 0; n < 4; ++n)
          acc[m][n] = __builtin_amdgcn_mfma_f32_16x16x32_bf16(afr[m], bfr[ks][n], acc[m][n], 0, 0, 0);
    }
  }

  float b1v[4];
#pragma unroll
  for (int n = 0; n < 4; ++n) b1v[n] = (half == 0) ? b1[wv * 64 + n * 16 + l15] : 0.f;

#pragma unroll
  for (int m = 0; m < 4; ++m)
#pragma unroll
    for (int n = 0; n < 4; ++n)
#pragma unroll
      for (int r = 0; r < 4; ++r) {
        int row = m * 16 + lhi * 4 + r;
        int col = wv * 64 + n * 16 + l15;
        int gr = n0 + row;
        if (gr < NNODES)
          Y[(size_t)gr * 512 + half * 256 + col] = f2bf(acc[m][n][r] + b1v[n]);
      }
}

// ---- edge kernel: gather Y1[src]+Y2[dst], relu, GEMM2 (K=256,N=16pad), log_softmax
// grid 5000, 256 threads; wave handles 16 edges.
__global__ __launch_bounds__(256) void k_edge(
    const int* __restrict__ ei,
    const unsigned short* __restrict__ Y,
    const unsigned short* __restrict__ w2f,
    const float* __restrict__ b2,
    float* __restrict__ out)
{
  const int tid  = threadIdx.x;
  const int lane = tid & 63;
  const int wv   = tid >> 6;
  const int e0   = blockIdx.x * 64;
  const int l15  = lane & 15;
  const int lhi  = lane >> 4;

  // A-frag row for this lane = edge (e0 + wv*16 + l15); k-offset = lhi*8
  int edge = e0 + wv * 16 + l15;
  int src = ei[edge];
  int dst = ei[E_TOTAL + edge];
  const unsigned short* py1 = Y + (size_t)src * 512 + lhi * 8;
  const unsigned short* py2 = Y + (size_t)dst * 512 + 256 + lhi * 8;

  bf16x8 bw[8];
#pragma unroll
  for (int kk = 0; kk < 8; ++kk)
    bw[kk] = *(const bf16x8*)(w2f + ((size_t)kk * 64 + lane) * 8);

  f32x4 lg = {0.f, 0.f, 0.f, 0.f};
#pragma unroll
  for (int kk = 0; kk < 8; ++kk) {
    u16x8 a = *(const u16x8*)(py1 + kk * 32);
    u16x8 b = *(const u16x8*)(py2 + kk * 32);
    u16x8 hh;
#pragma unroll
    for (int j = 0; j < 8; ++j) {
      float v = bf2f(a[j]) + bf2f(b[j]);
      hh[j] = f2bf(fmaxf(v, 0.f));
    }
    lg = __builtin_amdgcn_mfma_f32_16x16x32_bf16(
        __builtin_bit_cast(bf16x8, hh), bw[kk], lg, 0, 0, 0);
  }

  // + b2, log_softmax across the 16-lane class group (cols 10..15 padding)
  bool valid = (l15 < NCLS);
  float bias = valid ? b2[l15] : 0.f;
#pragma unroll
  for (int r = 0; r < 4; ++r) {
    float v = lg[r] + bias;
    float mv = valid ? v : -1e30f;
#pragma unroll
    for (int s = 1; s < 16; s <<= 1) mv = fmaxf(mv, __shfl_xor(mv, s, 64));
    float ev = valid ? __expf(v - mv) : 0.f;
    float sv = ev;
#pragma unroll
    for (int s = 1; s < 16; s <<= 1) sv += __shfl_xor(sv, s, 64);
    float res = v - mv - __logf(sv);
    if (valid) out[(size_t)(e0 + wv * 16 + lhi * 4 + r) * NCLS + l15] = res;
  }
}

extern "C" void kernel_launch(void* const* d_in, const int* in_sizes, int n_in,
                              void* d_out, int out_size, void* d_ws, size_t ws_size,
                              hipStream_t stream) {
  const float* x  = (const float*)d_in[0];
  const int*   ei = (const int*)d_in[1];
  const float* W1 = (const float*)d_in[2];
  const float* b1 = (const float*)d_in[3];
  const float* W2 = (const float*)d_in[4];
  const float* b2 = (const float*)d_in[5];
  float* out = (float*)d_out;

  unsigned short* xbf = (unsigned short*)d_ws;               // 2,560,000 u16
  unsigned short* w1f = xbf + (size_t)NNODES * HID;          // 131,072 u16
  unsigned short* w2f = w1f + (size_t)131072;                // 4,096 u16
  unsigned short* Yb  = w2f + (size_t)4096;                  // 5,120,000 u16

  k_x2bf<<<NNODES * HID / 8 / 256, 256, 0, stream>>>(x, xbf);
  k_w1frag<<<64, 256, 0, stream>>>(W1, w1f);
  k_w2frag<<<2, 256, 0, stream>>>(W2, w2f);
  k_prep<<<dim3((NNODES + 63) / 64, 2), 256, 0, stream>>>(xbf, w1f, b1, Yb);
  k_edge<<<E_TOTAL / 64, 256, 0, stream>>>(ei, Yb, w2f, b2, out);
}

// Round 3
// 74.035 us; speedup vs baseline: 1.5273x; 1.0633x over previous
//
#include <hip/hip_runtime.h>

#define E_TOTAL 320000
#define NNODES  10000
#define HID     256
#define NCLS    10

typedef __attribute__((ext_vector_type(4))) float f32x4;
typedef __attribute__((ext_vector_type(8))) __bf16 bf16x8;
typedef __attribute__((ext_vector_type(8))) unsigned short u16x8;

static __device__ __forceinline__ unsigned short f2bf(float f) {
  unsigned u = __builtin_bit_cast(unsigned, f);
  u += 0x7fffu + ((u >> 16) & 1u);
  return (unsigned short)(u >> 16);
}

// ---- prep: x f32 -> bf16 (row-major [NNODES][HID]) ----
__global__ void k_x2bf(const float* __restrict__ x, unsigned short* __restrict__ xbf) {
  int i = blockIdx.x * blockDim.x + threadIdx.x;  // one thread per 8 elems
  const f32x4* s = (const f32x4*)x + (size_t)i * 2;
  f32x4 a = s[0], b = s[1];
  u16x8 o;
  o[0]=f2bf(a[0]); o[1]=f2bf(a[1]); o[2]=f2bf(a[2]); o[3]=f2bf(a[3]);
  o[4]=f2bf(b[0]); o[5]=f2bf(b[1]); o[6]=f2bf(b[2]); o[7]=f2bf(b[3]);
  *((u16x8*)xbf + i) = o;
}

// ---- prep: W1 [512][256] -> B-fragment layout for the node-GEMM ----
// frag f = (half*16 + cb)*8 + kk ; elem (f*64+l)*8+j =
//   W1[half*256 + kk*32 + 8*(l>>4) + j][cb*16 + (l&15)]
__global__ void k_w1frag(const float* __restrict__ W1, unsigned short* __restrict__ w1f) {
  int gid = blockIdx.x * blockDim.x + threadIdx.x;  // 16384
  int l = gid & 63, kk = (gid >> 6) & 7, cb = (gid >> 9) & 15, half = gid >> 13;
  int kbase = half * 256 + kk * 32 + (l >> 4) * 8;
  int col = cb * 16 + (l & 15);
  u16x8 o;
#pragma unroll
  for (int j = 0; j < 8; ++j) o[j] = f2bf(W1[(size_t)(kbase + j) * HID + col]);
  *((u16x8*)w1f + gid) = o;
}

// ---- prep: W2 [256][10] -> padded (16-col) B-fragment layout bf16 ----
__global__ void k_w2frag(const float* __restrict__ W2, unsigned short* __restrict__ w2f) {
  int gid = blockIdx.x * blockDim.x + threadIdx.x;  // 512
  int l = gid & 63, kk = gid >> 6;                  // kk 0..7
  int kbase = kk * 32 + (l >> 4) * 8;
  int c = l & 15;
  u16x8 o;
#pragma unroll
  for (int j = 0; j < 8; ++j)
    o[j] = (c < NCLS) ? f2bf(W2[(size_t)(kbase + j) * NCLS + c]) : (unsigned short)0;
  *((u16x8*)w2f + gid) = o;
}

// ---- node GEMM: Y[n][half*256+col] = sum_k x[n][k]*W1[half*256+k][col] (+b1 if half==0)
// grid (313, 2), 256 threads. Tile 32 rows x 256 cols, K=256 (4 steps of 64).
__global__ __launch_bounds__(256, 3) void k_prep(
    const unsigned short* __restrict__ xbf,
    const unsigned short* __restrict__ w1f,
    const float* __restrict__ b1,
    unsigned short* __restrict__ Y)           // [NNODES][512] bf16
{
  __shared__ __align__(16) unsigned short ldsA[2][32 * 64];  // XOR-swizzled tiles

  const int tid  = threadIdx.x;
  const int lane = tid & 63;
  const int wv   = tid >> 6;
  const int n0   = blockIdx.x * 32;
  const int half = blockIdx.y;
  const int l15  = lane & 15;
  const int lhi  = lane >> 4;

  f32x4 acc[2][4] = {};

  auto stageA = [&](int kb, int buf) {
    int col0 = kb * 64;
    int r = wv * 8 + (lane >> 3);
    int gr = n0 + r; if (gr > NNODES - 1) gr = NNODES - 1;
    int usrc = (lane & 7) ^ (r & 7);
    const unsigned short* g = xbf + (size_t)gr * HID + col0 + usrc * 8;
    unsigned short* lp = &ldsA[buf][(wv * 8) * 64];
    __builtin_amdgcn_global_load_lds(
        (const __attribute__((address_space(1))) unsigned int*)g,
        (__attribute__((address_space(3))) unsigned int*)lp,
        16, 0, 0);
  };

  stageA(0, 0);

  for (int kb = 0; kb < 4; ++kb) {
    int buf = kb & 1;
    __syncthreads();
    if (kb < 3) stageA(kb + 1, buf ^ 1);

    bf16x8 bfr[2][4];
#pragma unroll
    for (int ks = 0; ks < 2; ++ks)
#pragma unroll
      for (int n = 0; n < 4; ++n) {
        int cb = wv * 4 + n;
        int kk = kb * 2 + ks;
        int f = (half * 16 + cb) * 8 + kk;
        bfr[ks][n] = *(const bf16x8*)(w1f + ((size_t)f * 64 + lane) * 8);
      }

#pragma unroll
    for (int ks = 0; ks < 2; ++ks) {
      bf16x8 afr[2];
#pragma unroll
      for (int m = 0; m < 2; ++m) {
        int row = m * 16 + l15;
        int boff = row * 128 + ((ks * 64 + lhi * 16) ^ ((row & 7) << 4));
        afr[m] = *(const bf16x8*)((const char*)&ldsA[buf][0] + boff);
      }
#pragma unroll
      for (int m = 0; m < 2; ++m)
#pragma unroll
        for (int n = 0; n < 4; ++n)
          acc[m][n] = __builtin_amdgcn_mfma_f32_16x16x32_bf16(afr[m], bfr[ks][n], acc[m][n], 0, 0, 0);
    }
  }

  float b1v[4];
#pragma unroll
  for (int n = 0; n < 4; ++n) b1v[n] = (half == 0) ? b1[wv * 64 + n * 16 + l15] : 0.f;

#pragma unroll
  for (int m = 0; m < 2; ++m)
#pragma unroll
    for (int n = 0; n < 4; ++n)
#pragma unroll
      for (int r = 0; r < 4; ++r) {
        int row = m * 16 + lhi * 4 + r;
        int col = wv * 64 + n * 16 + l15;
        int gr = n0 + row;
        if (gr < NNODES)
          Y[(size_t)gr * 512 + half * 256 + col] = f2bf(acc[m][n][r] + b1v[n]);
      }
}

// ---- edge kernel: gather Y1[src]+Y2[dst], relu, GEMM2 (K=256,N=16pad), log_softmax
// grid 5000, 256 threads; wave handles 16 edges. All gathers issued before compute.
__global__ __launch_bounds__(256) void k_edge(
    const int* __restrict__ ei,
    const unsigned short* __restrict__ Y,
    const unsigned short* __restrict__ w2f,
    const float* __restrict__ b2,
    float* __restrict__ out)
{
  const int tid  = threadIdx.x;
  const int lane = tid & 63;
  const int wv   = tid >> 6;
  const int e0   = blockIdx.x * 64;
  const int l15  = lane & 15;
  const int lhi  = lane >> 4;

  // A-frag row for this lane = edge (e0 + wv*16 + l15); k-offset = lhi*8
  int edge = e0 + wv * 16 + l15;
  int src = ei[edge];
  int dst = ei[E_TOTAL + edge];
  const bf16x8* py1 = (const bf16x8*)(Y + (size_t)src * 512 + lhi * 8);
  const bf16x8* py2 = (const bf16x8*)(Y + (size_t)dst * 512 + 256 + lhi * 8);

  // issue ALL gathers first — 16 independent loads in flight per wave
  bf16x8 ya[8], yb[8];
#pragma unroll
  for (int kk = 0; kk < 8; ++kk) ya[kk] = py1[kk * 4];
#pragma unroll
  for (int kk = 0; kk < 8; ++kk) yb[kk] = py2[kk * 4];

  bf16x8 bw[8];
#pragma unroll
  for (int kk = 0; kk < 8; ++kk)
    bw[kk] = *(const bf16x8*)(w2f + ((size_t)kk * 64 + lane) * 8);

  f32x4 lg = {0.f, 0.f, 0.f, 0.f};
#pragma unroll
  for (int kk = 0; kk < 8; ++kk) {
    bf16x8 a = ya[kk], b = yb[kk];
    bf16x8 hh;
#pragma unroll
    for (int j = 0; j < 8; ++j) {
      float v = (float)a[j] + (float)b[j];
      hh[j] = (__bf16)fmaxf(v, 0.f);
    }
    lg = __builtin_amdgcn_mfma_f32_16x16x32_bf16(hh, bw[kk], lg, 0, 0, 0);
  }

  // + b2, log_softmax across the 16-lane class group (cols 10..15 padding)
  bool valid = (l15 < NCLS);
  float bias = valid ? b2[l15] : 0.f;
#pragma unroll
  for (int r = 0; r < 4; ++r) {
    float v = lg[r] + bias;
    float mv = valid ? v : -1e30f;
#pragma unroll
    for (int s = 1; s < 16; s <<= 1) mv = fmaxf(mv, __shfl_xor(mv, s, 64));
    float ev = valid ? __expf(v - mv) : 0.f;
    float sv = ev;
#pragma unroll
    for (int s = 1; s < 16; s <<= 1) sv += __shfl_xor(sv, s, 64);
    float res = v - mv - __logf(sv);
    if (valid) out[(size_t)(e0 + wv * 16 + lhi * 4 + r) * NCLS + l15] = res;
  }
}

extern "C" void kernel_launch(void* const* d_in, const int* in_sizes, int n_in,
                              void* d_out, int out_size, void* d_ws, size_t ws_size,
                              hipStream_t stream) {
  const float* x  = (const float*)d_in[0];
  const int*   ei = (const int*)d_in[1];
  const float* W1 = (const float*)d_in[2];
  const float* b1 = (const float*)d_in[3];
  const float* W2 = (const float*)d_in[4];
  const float* b2 = (const float*)d_in[5];
  float* out = (float*)d_out;

  unsigned short* xbf = (unsigned short*)d_ws;               // 2,560,000 u16
  unsigned short* w1f = xbf + (size_t)NNODES * HID;          // 131,072 u16
  unsigned short* w2f = w1f + (size_t)131072;                // 4,096 u16
  unsigned short* Yb  = w2f + (size_t)4096;                  // 5,120,000 u16

  k_x2bf<<<NNODES * HID / 8 / 256, 256, 0, stream>>>(x, xbf);
  k_w1frag<<<64, 256, 0, stream>>>(W1, w1f);
  k_w2frag<<<2, 256, 0, stream>>>(W2, w2f);
  k_prep<<<dim3((NNODES + 31) / 32, 2), 256, 0, stream>>>(xbf, w1f, b1, Yb);
  k_edge<<<E_TOTAL / 64, 256, 0, stream>>>(ei, Yb, w2f, b2, out);
}

// Round 4
// 66.988 us; speedup vs baseline: 1.6880x; 1.1052x over previous
//
#include <hip/hip_runtime.h>

#define E_TOTAL 320000
#define NNODES  10000
#define HID     256
#define NCLS    10

typedef __attribute__((ext_vector_type(4))) float f32x4;
typedef __attribute__((ext_vector_type(8))) __bf16 bf16x8;
typedef __attribute__((ext_vector_type(8))) unsigned short u16x8;

static __device__ __forceinline__ unsigned short f2bf(float f) {
  unsigned u = __builtin_bit_cast(unsigned, f);
  u += 0x7fffu + ((u >> 16) & 1u);
  return (unsigned short)(u >> 16);
}

// ---- merged prep: x->bf16 | W1->frag | W2->frag, split by blockIdx ----
// blocks [0,1250): x2bf ; [1250,1314): w1frag ; [1314,1316): w2frag
__global__ void k_pack(const float* __restrict__ x,
                       const float* __restrict__ W1,
                       const float* __restrict__ W2,
                       unsigned short* __restrict__ xbf,
                       unsigned short* __restrict__ w1f,
                       unsigned short* __restrict__ w2f) {
  int b = blockIdx.x, tid = threadIdx.x;
  if (b < 1250) {
    int i = b * 256 + tid;                        // one thread per 8 elems
    const f32x4* s = (const f32x4*)x + (size_t)i * 2;
    f32x4 a = s[0], c = s[1];
    u16x8 o;
    o[0]=f2bf(a[0]); o[1]=f2bf(a[1]); o[2]=f2bf(a[2]); o[3]=f2bf(a[3]);
    o[4]=f2bf(c[0]); o[5]=f2bf(c[1]); o[6]=f2bf(c[2]); o[7]=f2bf(c[3]);
    *((u16x8*)xbf + i) = o;
  } else if (b < 1314) {
    int gid = (b - 1250) * 256 + tid;             // 16384
    int l = gid & 63, kk = (gid >> 6) & 7, cb = (gid >> 9) & 15, half = gid >> 13;
    int kbase = half * 256 + kk * 32 + (l >> 4) * 8;
    int col = cb * 16 + (l & 15);
    u16x8 o;
#pragma unroll
    for (int j = 0; j < 8; ++j) o[j] = f2bf(W1[(size_t)(kbase + j) * HID + col]);
    *((u16x8*)w1f + gid) = o;
  } else {
    int gid = (b - 1314) * 256 + tid;             // 512
    int l = gid & 63, kk = gid >> 6;
    int kbase = kk * 32 + (l >> 4) * 8;
    int c = l & 15;
    u16x8 o;
#pragma unroll
    for (int j = 0; j < 8; ++j)
      o[j] = (c < NCLS) ? f2bf(W2[(size_t)(kbase + j) * NCLS + c]) : (unsigned short)0;
    *((u16x8*)w2f + gid) = o;
  }
}

// ---- node GEMM: Y[n][half*256+col] = sum_k x[n][k]*W1[half*256+k][col] (+b1 if half==0)
__global__ __launch_bounds__(256, 3) void k_prep(
    const unsigned short* __restrict__ xbf,
    const unsigned short* __restrict__ w1f,
    const float* __restrict__ b1,
    unsigned short* __restrict__ Y)           // [NNODES][512] bf16
{
  __shared__ __align__(16) unsigned short ldsA[2][32 * 64];  // XOR-swizzled tiles

  const int tid  = threadIdx.x;
  const int lane = tid & 63;
  const int wv   = tid >> 6;
  const int n0   = blockIdx.x * 32;
  const int half = blockIdx.y;
  const int l15  = lane & 15;
  const int lhi  = lane >> 4;

  f32x4 acc[2][4] = {};

  auto stageA = [&](int kb, int buf) {
    int col0 = kb * 64;
    int r = wv * 8 + (lane >> 3);
    int gr = n0 + r; if (gr > NNODES - 1) gr = NNODES - 1;
    int usrc = (lane & 7) ^ (r & 7);
    const unsigned short* g = xbf + (size_t)gr * HID + col0 + usrc * 8;
    unsigned short* lp = &ldsA[buf][(wv * 8) * 64];
    __builtin_amdgcn_global_load_lds(
        (const __attribute__((address_space(1))) unsigned int*)g,
        (__attribute__((address_space(3))) unsigned int*)lp,
        16, 0, 0);
  };

  stageA(0, 0);

  for (int kb = 0; kb < 4; ++kb) {
    int buf = kb & 1;
    __syncthreads();
    if (kb < 3) stageA(kb + 1, buf ^ 1);

    bf16x8 bfr[2][4];
#pragma unroll
    for (int ks = 0; ks < 2; ++ks)
#pragma unroll
      for (int n = 0; n < 4; ++n) {
        int cb = wv * 4 + n;
        int kk = kb * 2 + ks;
        int f = (half * 16 + cb) * 8 + kk;
        bfr[ks][n] = *(const bf16x8*)(w1f + ((size_t)f * 64 + lane) * 8);
      }

#pragma unroll
    for (int ks = 0; ks < 2; ++ks) {
      bf16x8 afr[2];
#pragma unroll
      for (int m = 0; m < 2; ++m) {
        int row = m * 16 + l15;
        int boff = row * 128 + ((ks * 64 + lhi * 16) ^ ((row & 7) << 4));
        afr[m] = *(const bf16x8*)((const char*)&ldsA[buf][0] + boff);
      }
#pragma unroll
      for (int m = 0; m < 2; ++m)
#pragma unroll
        for (int n = 0; n < 4; ++n)
          acc[m][n] = __builtin_amdgcn_mfma_f32_16x16x32_bf16(afr[m], bfr[ks][n], acc[m][n], 0, 0, 0);
    }
  }

  float b1v[4];
#pragma unroll
  for (int n = 0; n < 4; ++n) b1v[n] = (half == 0) ? b1[wv * 64 + n * 16 + l15] : 0.f;

#pragma unroll
  for (int m = 0; m < 2; ++m)
#pragma unroll
    for (int n = 0; n < 4; ++n)
#pragma unroll
      for (int r = 0; r < 4; ++r) {
        int row = m * 16 + lhi * 4 + r;
        int col = wv * 64 + n * 16 + l15;
        int gr = n0 + row;
        if (gr < NNODES)
          Y[(size_t)gr * 512 + half * 256 + col] = f2bf(acc[m][n][r] + b1v[n]);
      }
}

// ---- edge kernel: gather Y1[src]+Y2[dst], relu, GEMM2 (K=256,N=16pad), log_softmax
// Wave handles 16 edges; all 16 gathers FORCED in flight via sched_barrier(0).
__global__ __launch_bounds__(256, 4) void k_edge(
    const int* __restrict__ ei,
    const unsigned short* __restrict__ Y,
    const unsigned short* __restrict__ w2f,
    const float* __restrict__ b2,
    float* __restrict__ out)
{
  __shared__ __align__(16) unsigned short ldsW[4096];   // w2 frags, 8 KB

  const int tid  = threadIdx.x;
  const int lane = tid & 63;
  const int wv   = tid >> 6;
  const int e0   = blockIdx.x * 64;
  const int l15  = lane & 15;
  const int lhi  = lane >> 4;

  int edge = e0 + wv * 16 + l15;
  int src = ei[edge];
  int dst = ei[E_TOTAL + edge];

  // stage w2f -> LDS BEFORE issuing gathers (the barrier's vmcnt drain is cheap here)
  {
    const u16x8* s = (const u16x8*)w2f;
    u16x8* d = (u16x8*)ldsW;
    d[tid] = s[tid];
    d[tid + 256] = s[tid + 256];
  }
  __syncthreads();

  const bf16x8* py1 = (const bf16x8*)(Y + (size_t)src * 512 + lhi * 8);
  const bf16x8* py2 = (const bf16x8*)(Y + (size_t)dst * 512 + 256 + lhi * 8);

  // issue ALL 16 gathers; sched_barrier(0) forbids the scheduler from sinking them
  bf16x8 ya[8], yb[8];
#pragma unroll
  for (int kk = 0; kk < 8; ++kk) {
    ya[kk] = py1[kk * 4];
    yb[kk] = py2[kk * 4];
  }
  __builtin_amdgcn_sched_barrier(0);

  f32x4 lg = {0.f, 0.f, 0.f, 0.f};
#pragma unroll
  for (int kk = 0; kk < 8; ++kk) {
    bf16x8 bw = *(const bf16x8*)(ldsW + kk * 512 + lane * 8);
    bf16x8 a = ya[kk], b = yb[kk];
    bf16x8 hh;
#pragma unroll
    for (int j = 0; j < 8; ++j) {
      float v = (float)a[j] + (float)b[j];
      hh[j] = (__bf16)fmaxf(v, 0.f);
    }
    lg = __builtin_amdgcn_mfma_f32_16x16x32_bf16(hh, bw, lg, 0, 0, 0);
  }

  // + b2, log_softmax across the 16-lane class group (cols 10..15 padding)
  bool valid = (l15 < NCLS);
  float bias = valid ? b2[l15] : 0.f;
#pragma unroll
  for (int r = 0; r < 4; ++r) {
    float v = lg[r] + bias;
    float mv = valid ? v : -1e30f;
#pragma unroll
    for (int s = 1; s < 16; s <<= 1) mv = fmaxf(mv, __shfl_xor(mv, s, 64));
    float ev = valid ? __expf(v - mv) : 0.f;
    float sv = ev;
#pragma unroll
    for (int s = 1; s < 16; s <<= 1) sv += __shfl_xor(sv, s, 64);
    float res = v - mv - __logf(sv);
    if (valid) out[(size_t)(e0 + wv * 16 + lhi * 4 + r) * NCLS + l15] = res;
  }
}

extern "C" void kernel_launch(void* const* d_in, const int* in_sizes, int n_in,
                              void* d_out, int out_size, void* d_ws, size_t ws_size,
                              hipStream_t stream) {
  const float* x  = (const float*)d_in[0];
  const int*   ei = (const int*)d_in[1];
  const float* W1 = (const float*)d_in[2];
  const float* b1 = (const float*)d_in[3];
  const float* W2 = (const float*)d_in[4];
  const float* b2 = (const float*)d_in[5];
  float* out = (float*)d_out;

  unsigned short* xbf = (unsigned short*)d_ws;               // 2,560,000 u16
  unsigned short* w1f = xbf + (size_t)NNODES * HID;          // 131,072 u16
  unsigned short* w2f = w1f + (size_t)131072;                // 4,096 u16
  unsigned short* Yb  = w2f + (size_t)4096;                  // 5,120,000 u16

  k_pack<<<1316, 256, 0, stream>>>(x, W1, W2, xbf, w1f, w2f);
  k_prep<<<dim3((NNODES + 31) / 32, 2), 256, 0, stream>>>(xbf, w1f, b1, Yb);
  k_edge<<<E_TOTAL / 64, 256, 0, stream>>>(ei, Yb, w2f, b2, out);
}